// Round 1
// baseline (236.290 us; speedup 1.0000x reference)
//
#include <hip/hip_runtime.h>
#include <hip/hip_bf16.h>
#include <math.h>

#define S_LEN 2048
#define DIM   1024
#define NH    16
#define NL    4
#define NB    2

typedef __attribute__((ext_vector_type(8))) short bf16x8;
typedef __attribute__((ext_vector_type(4))) float f32x4;
typedef unsigned short u16;

__device__ __forceinline__ float bf2f(u16 u) {
  union { unsigned int i; float f; } x; x.i = ((unsigned int)u) << 16; return x.f;
}
__device__ __forceinline__ u16 f2bf(float f) {  // RNE
  union { float f; unsigned int i; } x; x.f = f;
  unsigned int r = x.i + 0x7fffu + ((x.i >> 16) & 1u);
  return (u16)(r >> 16);
}

__device__ __forceinline__ void g2l16(const void* g, void* l) {
  __builtin_amdgcn_global_load_lds(
      (const __attribute__((address_space(1))) void*)g,
      (__attribute__((address_space(3))) void*)l, 16, 0, 0);
}

__global__ void cvt_f32_bf16(const float* __restrict__ in, u16* __restrict__ out, int n4) {
  int i = blockIdx.x * blockDim.x + threadIdx.x;
  if (i >= n4) return;
  float4 v = ((const float4*)in)[i];
  ushort4 o;
  o.x = f2bf(v.x); o.y = f2bf(v.y); o.z = f2bf(v.z); o.w = f2bf(v.w);
  ((ushort4*)out)[i] = o;
}

// C = act(A @ Bt^T + bias). A:[M][K] bf16, Bt:[N][K] bf16 (row-major), bias f32[N].
// 128x128 tile, BK=64, 4 waves (2x2), each wave 64x64 via 4x4 MFMA 16x16x32.
// LDS tiles [128][64] bf16 with XOR swizzle (byte ^= (row&7)<<4), staged with
// global_load_lds width=16 (linear dest + pre-swizzled source).
template <bool GELU, typename OT>
__global__ __launch_bounds__(256)
void gemm_bt(const u16* __restrict__ A, const u16* __restrict__ Bt,
             const float* __restrict__ bias, OT* __restrict__ C,
             int M, int N, int K) {
  __shared__ u16 As[128 * 64];
  __shared__ u16 Bs[128 * 64];
  const int lane = threadIdx.x & 63, wave = threadIdx.x >> 6;
  const int ln = lane & 15, g = lane >> 4;
  const int m0 = blockIdx.y * 128, n0 = blockIdx.x * 128;
  const int wm = wave >> 1, wn = wave & 1;
  f32x4 acc[4][4] = {};

  for (int k0 = 0; k0 < K; k0 += 64) {
    __syncthreads();
#pragma unroll
    for (int rd = 0; rd < 4; ++rd) {
      int chunk = rd * 4 + wave;               // 16 x 1KB chunks per tile
      int flat = chunk * 1024 + lane * 16;     // linear LDS byte
      int row = flat >> 7;                     // 128B per row
      int within = (flat & 127) ^ ((row & 7) << 4);  // pre-swizzled source
      g2l16((const char*)A + ((size_t)(m0 + row) * K + k0) * 2 + within,
            (char*)As + chunk * 1024);
      g2l16((const char*)Bt + ((size_t)(n0 + row) * K + k0) * 2 + within,
            (char*)Bs + chunk * 1024);
    }
    __syncthreads();
#pragma unroll
    for (int kc = 0; kc < 2; ++kc) {
      bf16x8 af[4], bfr[4];
#pragma unroll
      for (int i = 0; i < 4; ++i) {
        int ra = wm * 64 + i * 16 + ln;
        af[i] = *(const bf16x8*)((const char*)As + ra * 128 +
                                 ((kc * 64 + g * 16) ^ ((ra & 7) << 4)));
        int rb = wn * 64 + i * 16 + ln;
        bfr[i] = *(const bf16x8*)((const char*)Bs + rb * 128 +
                                  ((kc * 64 + g * 16) ^ ((rb & 7) << 4)));
      }
#pragma unroll
      for (int i = 0; i < 4; ++i)
#pragma unroll
        for (int j = 0; j < 4; ++j)
          acc[i][j] = __builtin_amdgcn_mfma_f32_16x16x32_bf16(af[i], bfr[j], acc[i][j], 0, 0, 0);
    }
  }

#pragma unroll
  for (int j = 0; j < 4; ++j) {
    int gc = n0 + wn * 64 + j * 16 + ln;
    float bv = bias[gc];
#pragma unroll
    for (int i = 0; i < 4; ++i) {
      int gr0 = m0 + wm * 64 + i * 16 + g * 4;
#pragma unroll
      for (int r = 0; r < 4; ++r) {
        float v = acc[i][j][r] + bv;
        if constexpr (GELU) v = 0.5f * v * (1.0f + erff(v * 0.70710678118f));
        if constexpr (sizeof(OT) == 2) C[(size_t)(gr0 + r) * N + gc] = (OT)f2bf(v);
        else                           C[(size_t)(gr0 + r) * N + gc] = (OT)v;
      }
    }
  }
}

// Fused self-attention (keys/queries both = Q) + per-row memory slots.
// grid (S/64, H, B), 256 threads = 4 waves x 16 q-rows.
__global__ __launch_bounds__(256)
void attn(const u16* __restrict__ Q, const u16* __restrict__ Xb,
          const float* __restrict__ PQ, const float* __restrict__ PV,
          u16* __restrict__ CTX) {
  __shared__ u16 Ks[64 * 64];        // K tile, swizzled
  __shared__ u16 Vt[64 * 64];        // V^T tile [d][key], swizzled
  __shared__ u16 Pw[4][16 * 64];     // per-wave P, swizzled
  __shared__ float ctxs[4][16][64];
  __shared__ float statm[4][16], statl[4][16];

  const int lane = threadIdx.x & 63, wave = threadIdx.x >> 6;
  const int ln = lane & 15, g = lane >> 4;
  const int qt = blockIdx.x, h = blockIdx.y, b = blockIdx.z;

  const size_t qrow = (size_t)b * S_LEN + qt * 64 + wave * 16 + ln;
  const bf16x8 qa0 = *(const bf16x8*)(Q + qrow * DIM + h * 64 + g * 8);
  const bf16x8 qa1 = *(const bf16x8*)(Q + qrow * DIM + h * 64 + 32 + g * 8);

  f32x4 acc[4] = {};
  float m_run[4] = {-INFINITY, -INFINITY, -INFINITY, -INFINITY};
  float l_run[4] = {0.f, 0.f, 0.f, 0.f};

  const int tid = threadIdx.x;
  const int vr0 = (tid >> 3) * 2;   // key row pair
  const int vc0 = (tid & 7) * 8;    // dim cols

  for (int kt = 0; kt <= qt; ++kt) {
    __syncthreads();
    // stage K tile (rows of Q) via global_load_lds, pre-swizzled source
#pragma unroll
    for (int rd = 0; rd < 2; ++rd) {
      int chunk = rd * 4 + wave;
      int flat = chunk * 1024 + lane * 16;
      int row = flat >> 7;
      int within = (flat & 127) ^ ((row & 7) << 4);
      g2l16((const char*)Q + (((size_t)b * S_LEN + kt * 64 + row) * DIM + h * 64) * 2 + within,
            (char*)Ks + chunk * 1024);
    }
    // stage V^T (V = x head slice), transposed + swizzled writes
    {
      const u16* xsrc = Xb + ((size_t)b * S_LEN + kt * 64 + vr0) * DIM + h * 64 + vc0;
      bf16x8 r0 = *(const bf16x8*)xsrc;
      bf16x8 r1 = *(const bf16x8*)(xsrc + DIM);
#pragma unroll
      for (int j = 0; j < 8; ++j) {
        int c = vc0 + j;
        unsigned int pack = (unsigned int)(u16)r0[j] | ((unsigned int)(u16)r1[j] << 16);
        *(unsigned int*)((char*)Vt + c * 128 + ((vr0 * 2) ^ ((c & 7) << 4))) = pack;
      }
    }
    __syncthreads();

    // QK^T: 4 key-subtiles x (K=64 as 2 chunks)
    float p[4][4];
#pragma unroll
    for (int sub = 0; sub < 4; ++sub) {
      int kr = sub * 16 + ln;
      bf16x8 kb0 = *(const bf16x8*)((const char*)Ks + kr * 128 + ((g * 16) ^ ((kr & 7) << 4)));
      bf16x8 kb1 = *(const bf16x8*)((const char*)Ks + kr * 128 + ((64 + g * 16) ^ ((kr & 7) << 4)));
      f32x4 c = {};
      c = __builtin_amdgcn_mfma_f32_16x16x32_bf16(qa0, kb0, c, 0, 0, 0);
      c = __builtin_amdgcn_mfma_f32_16x16x32_bf16(qa1, kb1, c, 0, 0, 0);
#pragma unroll
      for (int r = 0; r < 4; ++r) {
        float s = c[r] * 0.125f;
        if (kt == qt) {
          int key = sub * 16 + ln;
          int qi = wave * 16 + g * 4 + r;
          if (key > qi) s = -INFINITY;
        }
        p[sub][r] = s;
      }
    }
    // online softmax (rows live in 16-lane groups; xor 1/2/4/8 stays in-group)
    float scl[4];
#pragma unroll
    for (int r = 0; r < 4; ++r) {
      float t = fmaxf(fmaxf(p[0][r], p[1][r]), fmaxf(p[2][r], p[3][r]));
      t = fmaxf(t, __shfl_xor(t, 1));
      t = fmaxf(t, __shfl_xor(t, 2));
      t = fmaxf(t, __shfl_xor(t, 4));
      t = fmaxf(t, __shfl_xor(t, 8));
      float mn = fmaxf(m_run[r], t);
      scl[r] = __expf(m_run[r] - mn);
      m_run[r] = mn;
    }
#pragma unroll
    for (int sub = 0; sub < 4; ++sub)
#pragma unroll
      for (int r = 0; r < 4; ++r) p[sub][r] = __expf(p[sub][r] - m_run[r]);
#pragma unroll
    for (int r = 0; r < 4; ++r) {
      float su = p[0][r] + p[1][r] + p[2][r] + p[3][r];
      su += __shfl_xor(su, 1);
      su += __shfl_xor(su, 2);
      su += __shfl_xor(su, 4);
      su += __shfl_xor(su, 8);
      l_run[r] = l_run[r] * scl[r] + su;
    }
#pragma unroll
    for (int ns = 0; ns < 4; ++ns)
#pragma unroll
      for (int r = 0; r < 4; ++r) acc[ns][r] *= scl[r];

    // P: C-layout -> LDS -> A-layout (per-wave private; wave-ordered ds ops)
#pragma unroll
    for (int sub = 0; sub < 4; ++sub)
#pragma unroll
      for (int r = 0; r < 4; ++r) {
        int pr = g * 4 + r;
        *(u16*)((char*)Pw[wave] + pr * 128 + (((sub * 16 + ln) * 2) ^ ((pr & 7) << 4))) =
            f2bf(p[sub][r]);
      }
    bf16x8 pa0 = *(const bf16x8*)((const char*)Pw[wave] + ln * 128 + ((g * 16) ^ ((ln & 7) << 4)));
    bf16x8 pa1 = *(const bf16x8*)((const char*)Pw[wave] + ln * 128 + ((64 + g * 16) ^ ((ln & 7) << 4)));
#pragma unroll
    for (int ns = 0; ns < 4; ++ns) {
      int vr = ns * 16 + ln;
      bf16x8 vb0 = *(const bf16x8*)((const char*)Vt + vr * 128 + ((g * 16) ^ ((vr & 7) << 4)));
      bf16x8 vb1 = *(const bf16x8*)((const char*)Vt + vr * 128 + ((64 + g * 16) ^ ((vr & 7) << 4)));
      acc[ns] = __builtin_amdgcn_mfma_f32_16x16x32_bf16(pa0, vb0, acc[ns], 0, 0, 0);
      acc[ns] = __builtin_amdgcn_mfma_f32_16x16x32_bf16(pa1, vb1, acc[ns], 0, 0, 0);
    }
  }

  // park state in LDS, remap to row-per-iteration x 64-lane dims
#pragma unroll
  for (int ns = 0; ns < 4; ++ns)
#pragma unroll
    for (int r = 0; r < 4; ++r) ctxs[wave][g * 4 + r][ns * 16 + ln] = acc[ns][r];
  if (ln == 0) {
#pragma unroll
    for (int r = 0; r < 4; ++r) {
      statm[wave][g * 4 + r] = m_run[r];
      statl[wave][g * 4 + r] = l_run[r];
    }
  }
  __syncthreads();

  // memory-slot epilogue: 4 extra softmax entries per row, then normalize
  for (int i = 0; i < 16; ++i) {
    int srow = qt * 64 + wave * 16 + i;
    size_t grow = (size_t)b * S_LEN + srow;
    float qd = bf2f(Q[grow * DIM + h * 64 + lane]);
    float mr = statm[wave][i];
    float lr = statl[wave][i];
    const float* pq = PQ + ((size_t)(b * NH + h) * S_LEN + srow) * NL * 64;
    const float* pv = PV + ((size_t)(b * NH + h) * S_LEN + srow) * NL * 64;
    float sc[4];
    float best = mr;
#pragma unroll
    for (int lm = 0; lm < 4; ++lm) {
      float prod = qd * pq[lm * 64 + lane];
#pragma unroll
      for (int o = 1; o < 64; o <<= 1) prod += __shfl_xor(prod, o);
      sc[lm] = prod * 0.125f;
      best = fmaxf(best, sc[lm]);
    }
    float scale = __expf(mr - best);
    float lnew = lr * scale;
    float cd = ctxs[wave][i][lane] * scale;
#pragma unroll
    for (int lm = 0; lm < 4; ++lm) {
      float wg = __expf(sc[lm] - best);
      lnew += wg;
      cd += wg * pv[lm * 64 + lane];
    }
    CTX[grow * DIM + h * 64 + lane] = f2bf(cd / lnew);
  }
}

extern "C" void kernel_launch(void* const* d_in, const int* in_sizes, int n_in,
                              void* d_out, int out_size, void* d_ws, size_t ws_size,
                              hipStream_t stream) {
  const float* x  = (const float*)d_in[0];
  const float* pq = (const float*)d_in[1];
  const float* pv = (const float*)d_in[2];
  const float* Wq = (const float*)d_in[3];
  const float* bq = (const float*)d_in[4];
  const float* Wo = (const float*)d_in[5];
  const float* bo = (const float*)d_in[6];
  float* out = (float*)d_out;

  const int M = NB * S_LEN;  // 4096
  u16* Qws  = (u16*)d_ws;                    // 8 MB
  u16* Cws  = Qws + (size_t)M * DIM;         // 8 MB
  u16* xbf  = Cws + (size_t)M * DIM;         // 8 MB
  u16* Wqbf = xbf + (size_t)M * DIM;         // 2 MB
  u16* Wobf = Wqbf + (size_t)DIM * DIM;      // 2 MB

  const int n4x = M * DIM / 4, n4w = DIM * DIM / 4;
  cvt_f32_bf16<<<(n4x + 255) / 256, 256, 0, stream>>>(x, xbf, n4x);
  cvt_f32_bf16<<<(n4w + 255) / 256, 256, 0, stream>>>(Wq, Wqbf, n4w);
  cvt_f32_bf16<<<(n4w + 255) / 256, 256, 0, stream>>>(Wo, Wobf, n4w);

  gemm_bt<false, u16><<<dim3(DIM / 128, M / 128), 256, 0, stream>>>(
      xbf, Wqbf, bq, Qws, M, DIM, DIM);
  attn<<<dim3(S_LEN / 64, NH, NB), 256, 0, stream>>>(Qws, xbf, pq, pv, Cws);
  gemm_bt<true, float><<<dim3(DIM / 128, M / 128), 256, 0, stream>>>(
      Cws, Wobf, bo, out, M, DIM, DIM);
}

// Round 2
// 235.306 us; speedup vs baseline: 1.0042x; 1.0042x over previous
//
#include <hip/hip_runtime.h>
#include <hip/hip_bf16.h>
#include <math.h>

#define S_LEN 2048
#define DIM   1024
#define NH    16
#define NL    4
#define NB    2

typedef __attribute__((ext_vector_type(8))) short bf16x8;
typedef __attribute__((ext_vector_type(4))) float f32x4;
typedef unsigned short u16;

__device__ __forceinline__ float bf2f(u16 u) {
  union { unsigned int i; float f; } x; x.i = ((unsigned int)u) << 16; return x.f;
}
__device__ __forceinline__ u16 f2bf(float f) {  // RNE
  union { float f; unsigned int i; } x; x.f = f;
  unsigned int r = x.i + 0x7fffu + ((x.i >> 16) & 1u);
  return (u16)(r >> 16);
}

__device__ __forceinline__ void g2l16(const void* g, void* l) {
  __builtin_amdgcn_global_load_lds(
      (const __attribute__((address_space(1))) void*)g,
      (__attribute__((address_space(3))) void*)l, 16, 0, 0);
}

__global__ void cvt_f32_bf16(const float* __restrict__ in, u16* __restrict__ out, int n4) {
  int i = blockIdx.x * blockDim.x + threadIdx.x;
  if (i >= n4) return;
  float4 v = ((const float4*)in)[i];
  ushort4 o;
  o.x = f2bf(v.x); o.y = f2bf(v.y); o.z = f2bf(v.z); o.w = f2bf(v.w);
  ((ushort4*)out)[i] = o;
}

// C = act(A @ Bt^T + bias). A:[M][K] bf16, Bt:[N][K] bf16 (row-major), bias f32[N].
// 128x128 tile, BK=64, 4 waves (2x2), each wave 64x64 via 4x4 MFMA 16x16x32.
template <bool GELU, typename OT>
__global__ __launch_bounds__(256)
void gemm_bt(const u16* __restrict__ A, const u16* __restrict__ Bt,
             const float* __restrict__ bias, OT* __restrict__ C,
             int M, int N, int K) {
  __shared__ u16 As[128 * 64];
  __shared__ u16 Bs[128 * 64];
  const int lane = threadIdx.x & 63, wave = threadIdx.x >> 6;
  const int ln = lane & 15, g = lane >> 4;
  const int m0 = blockIdx.y * 128, n0 = blockIdx.x * 128;
  const int wm = wave >> 1, wn = wave & 1;
  f32x4 acc[4][4] = {};

  for (int k0 = 0; k0 < K; k0 += 64) {
    __syncthreads();
#pragma unroll
    for (int rd = 0; rd < 4; ++rd) {
      int chunk = rd * 4 + wave;               // 16 x 1KB chunks per tile
      int flat = chunk * 1024 + lane * 16;     // linear LDS byte
      int row = flat >> 7;                     // 128B per row
      int within = (flat & 127) ^ ((row & 7) << 4);  // pre-swizzled source
      g2l16((const char*)A + ((size_t)(m0 + row) * K + k0) * 2 + within,
            (char*)As + chunk * 1024);
      g2l16((const char*)Bt + ((size_t)(n0 + row) * K + k0) * 2 + within,
            (char*)Bs + chunk * 1024);
    }
    __syncthreads();
#pragma unroll
    for (int kc = 0; kc < 2; ++kc) {
      bf16x8 af[4], bfr[4];
#pragma unroll
      for (int i = 0; i < 4; ++i) {
        int ra = wm * 64 + i * 16 + ln;
        af[i] = *(const bf16x8*)((const char*)As + ra * 128 +
                                 ((kc * 64 + g * 16) ^ ((ra & 7) << 4)));
        int rb = wn * 64 + i * 16 + ln;
        bfr[i] = *(const bf16x8*)((const char*)Bs + rb * 128 +
                                  ((kc * 64 + g * 16) ^ ((rb & 7) << 4)));
      }
#pragma unroll
      for (int i = 0; i < 4; ++i)
#pragma unroll
        for (int j = 0; j < 4; ++j)
          acc[i][j] = __builtin_amdgcn_mfma_f32_16x16x32_bf16(af[i], bfr[j], acc[i][j], 0, 0, 0);
    }
  }

#pragma unroll
  for (int j = 0; j < 4; ++j) {
    int gc = n0 + wn * 64 + j * 16 + ln;
    float bv = bias[gc];
#pragma unroll
    for (int i = 0; i < 4; ++i) {
      int gr0 = m0 + wm * 64 + i * 16 + g * 4;
#pragma unroll
      for (int r = 0; r < 4; ++r) {
        float v = acc[i][j][r] + bv;
        if constexpr (GELU) v = 0.5f * v * (1.0f + erff(v * 0.70710678118f));
        if constexpr (sizeof(OT) == 2) C[(size_t)(gr0 + r) * N + gc] = (OT)f2bf(v);
        else                           C[(size_t)(gr0 + r) * N + gc] = (OT)v;
      }
    }
  }
}

// Flash self-attention, token part only. Writes normalized token ctx (f32)
// + per-row running max / denom. grid (S/64, H, B), 4 waves x 16 q-rows.
// Largest q-tiles dispatched first for load balance.
__global__ __launch_bounds__(256)
void attn(const u16* __restrict__ Q, const u16* __restrict__ Xb,
          float* __restrict__ CTXf, float* __restrict__ Mb, float* __restrict__ Lb) {
  __shared__ u16 Ks[64 * 64];        // K tile, swizzled
  __shared__ u16 Vt[64 * 64];        // V^T tile [d][key], swizzled
  __shared__ u16 Pw[4][16 * 64];     // per-wave P, swizzled

  const int lane = threadIdx.x & 63, wave = threadIdx.x >> 6;
  const int ln = lane & 15, g = lane >> 4;
  const int qt = gridDim.x - 1 - blockIdx.x;   // big tiles first
  const int h = blockIdx.y, b = blockIdx.z;

  const size_t qrow = (size_t)b * S_LEN + qt * 64 + wave * 16 + ln;
  const bf16x8 qa0 = *(const bf16x8*)(Q + qrow * DIM + h * 64 + g * 8);
  const bf16x8 qa1 = *(const bf16x8*)(Q + qrow * DIM + h * 64 + 32 + g * 8);

  f32x4 acc[4] = {};
  float m_run[4] = {-INFINITY, -INFINITY, -INFINITY, -INFINITY};
  float l_run[4] = {0.f, 0.f, 0.f, 0.f};

  const int tid = threadIdx.x;
  const int vr0 = (tid >> 3) * 2;   // key row pair
  const int vc0 = (tid & 7) * 8;    // dim cols

  for (int kt = 0; kt <= qt; ++kt) {
    __syncthreads();
    // stage K tile (rows of Q) via global_load_lds, pre-swizzled source
#pragma unroll
    for (int rd = 0; rd < 2; ++rd) {
      int chunk = rd * 4 + wave;
      int flat = chunk * 1024 + lane * 16;
      int row = flat >> 7;
      int within = (flat & 127) ^ ((row & 7) << 4);
      g2l16((const char*)Q + (((size_t)b * S_LEN + kt * 64 + row) * DIM + h * 64) * 2 + within,
            (char*)Ks + chunk * 1024);
    }
    // stage V^T (V = x head slice), transposed + swizzled writes
    {
      const u16* xsrc = Xb + ((size_t)b * S_LEN + kt * 64 + vr0) * DIM + h * 64 + vc0;
      bf16x8 r0 = *(const bf16x8*)xsrc;
      bf16x8 r1 = *(const bf16x8*)(xsrc + DIM);
#pragma unroll
      for (int j = 0; j < 8; ++j) {
        int c = vc0 + j;
        unsigned int pack = (unsigned int)(u16)r0[j] | ((unsigned int)(u16)r1[j] << 16);
        *(unsigned int*)((char*)Vt + c * 128 + ((vr0 * 2) ^ ((c & 7) << 4))) = pack;
      }
    }
    __syncthreads();

    // QK^T: 4 key-subtiles x (K=64 as 2 chunks)
    float p[4][4];
#pragma unroll
    for (int sub = 0; sub < 4; ++sub) {
      int kr = sub * 16 + ln;
      bf16x8 kb0 = *(const bf16x8*)((const char*)Ks + kr * 128 + ((g * 16) ^ ((kr & 7) << 4)));
      bf16x8 kb1 = *(const bf16x8*)((const char*)Ks + kr * 128 + ((64 + g * 16) ^ ((kr & 7) << 4)));
      f32x4 c = {};
      c = __builtin_amdgcn_mfma_f32_16x16x32_bf16(qa0, kb0, c, 0, 0, 0);
      c = __builtin_amdgcn_mfma_f32_16x16x32_bf16(qa1, kb1, c, 0, 0, 0);
#pragma unroll
      for (int r = 0; r < 4; ++r) {
        float s = c[r] * 0.125f;
        if (kt == qt) {
          int key = sub * 16 + ln;
          int qi = wave * 16 + g * 4 + r;
          if (key > qi) s = -INFINITY;
        }
        p[sub][r] = s;
      }
    }
    // online softmax (rows live in 16-lane groups; xor 1/2/4/8 stays in-group)
    float scl[4];
#pragma unroll
    for (int r = 0; r < 4; ++r) {
      float t = fmaxf(fmaxf(p[0][r], p[1][r]), fmaxf(p[2][r], p[3][r]));
      t = fmaxf(t, __shfl_xor(t, 1));
      t = fmaxf(t, __shfl_xor(t, 2));
      t = fmaxf(t, __shfl_xor(t, 4));
      t = fmaxf(t, __shfl_xor(t, 8));
      float mn = fmaxf(m_run[r], t);
      scl[r] = __expf(m_run[r] - mn);
      m_run[r] = mn;
    }
#pragma unroll
    for (int sub = 0; sub < 4; ++sub)
#pragma unroll
      for (int r = 0; r < 4; ++r) p[sub][r] = __expf(p[sub][r] - m_run[r]);
#pragma unroll
    for (int r = 0; r < 4; ++r) {
      float su = p[0][r] + p[1][r] + p[2][r] + p[3][r];
      su += __shfl_xor(su, 1);
      su += __shfl_xor(su, 2);
      su += __shfl_xor(su, 4);
      su += __shfl_xor(su, 8);
      l_run[r] = l_run[r] * scl[r] + su;
    }
#pragma unroll
    for (int ns = 0; ns < 4; ++ns)
#pragma unroll
      for (int r = 0; r < 4; ++r) acc[ns][r] *= scl[r];

    // P: C-layout -> LDS -> A-layout (per-wave private)
#pragma unroll
    for (int sub = 0; sub < 4; ++sub)
#pragma unroll
      for (int r = 0; r < 4; ++r) {
        int pr = g * 4 + r;
        *(u16*)((char*)Pw[wave] + pr * 128 + (((sub * 16 + ln) * 2) ^ ((pr & 7) << 4))) =
            f2bf(p[sub][r]);
      }
    bf16x8 pa0 = *(const bf16x8*)((const char*)Pw[wave] + ln * 128 + ((g * 16) ^ ((ln & 7) << 4)));
    bf16x8 pa1 = *(const bf16x8*)((const char*)Pw[wave] + ln * 128 + ((64 + g * 16) ^ ((ln & 7) << 4)));
#pragma unroll
    for (int ns = 0; ns < 4; ++ns) {
      int vr = ns * 16 + ln;
      bf16x8 vb0 = *(const bf16x8*)((const char*)Vt + vr * 128 + ((g * 16) ^ ((vr & 7) << 4)));
      bf16x8 vb1 = *(const bf16x8*)((const char*)Vt + vr * 128 + ((64 + g * 16) ^ ((vr & 7) << 4)));
      acc[ns] = __builtin_amdgcn_mfma_f32_16x16x32_bf16(pa0, vb0, acc[ns], 0, 0, 0);
      acc[ns] = __builtin_amdgcn_mfma_f32_16x16x32_bf16(pa1, vb1, acc[ns], 0, 0, 0);
    }
  }

  // write normalized token ctx (f32) + stats
  float inv_l[4];
#pragma unroll
  for (int r = 0; r < 4; ++r) inv_l[r] = 1.0f / l_run[r];
#pragma unroll
  for (int ns = 0; ns < 4; ++ns)
#pragma unroll
    for (int r = 0; r < 4; ++r) {
      int q = qt * 64 + wave * 16 + g * 4 + r;
      CTXf[((size_t)b * S_LEN + q) * DIM + h * 64 + ns * 16 + ln] = acc[ns][r] * inv_l[r];
    }
  if (ln == 0) {
#pragma unroll
    for (int r = 0; r < 4; ++r) {
      int q = qt * 64 + wave * 16 + g * 4 + r;
      size_t row = ((size_t)(b * NH + h)) * S_LEN + q;
      Mb[row] = m_run[r];
      Lb[row] = l_run[r];
    }
  }
}

// Fold the L=4 memory slots into the softmax + produce final bf16 ctx.
// One wave per (b,h,s) row. Pure streaming: reads past_q + past_v once.
__global__ __launch_bounds__(256)
void finalize(const u16* __restrict__ Q, const float* __restrict__ PQ,
              const float* __restrict__ PV, const float* __restrict__ CTXf,
              const float* __restrict__ Mb, const float* __restrict__ Lb,
              u16* __restrict__ Cout) {
  const int lane = threadIdx.x & 63, wave = threadIdx.x >> 6;
  const size_t row = (size_t)blockIdx.x * 4 + wave;  // over B*H*S, = (b*H+h)*S+s
  const int s = (int)(row & (S_LEN - 1));
  const int h = (int)((row >> 11) & (NH - 1));
  const int b = (int)(row >> 15);

  const float qd = bf2f(Q[((size_t)b * S_LEN + s) * DIM + h * 64 + lane]);
  const float* pq = PQ + row * (NL * 64);
  const float* pv = PV + row * (NL * 64);

  float msc[NL];
  float m_tok = Mb[row];
  float l_tok = Lb[row];
  float m_fin = m_tok;
#pragma unroll
  for (int lm = 0; lm < NL; ++lm) {
    float prod = qd * pq[lm * 64 + lane];
#pragma unroll
    for (int o = 1; o < 64; o <<= 1) prod += __shfl_xor(prod, o);
    msc[lm] = prod * 0.125f;
    m_fin = fmaxf(m_fin, msc[lm]);
  }
  const float a = __expf(m_tok - m_fin);
  float l_fin = l_tok * a;
  float cd = CTXf[((size_t)b * S_LEN + s) * DIM + h * 64 + lane] * (l_tok * a);
#pragma unroll
  for (int lm = 0; lm < NL; ++lm) {
    float w = __expf(msc[lm] - m_fin);
    l_fin += w;
    cd += w * pv[lm * 64 + lane];
  }
  Cout[((size_t)b * S_LEN + s) * DIM + h * 64 + lane] = f2bf(cd / l_fin);
}

extern "C" void kernel_launch(void* const* d_in, const int* in_sizes, int n_in,
                              void* d_out, int out_size, void* d_ws, size_t ws_size,
                              hipStream_t stream) {
  const float* x  = (const float*)d_in[0];
  const float* pq = (const float*)d_in[1];
  const float* pv = (const float*)d_in[2];
  const float* Wq = (const float*)d_in[3];
  const float* bq = (const float*)d_in[4];
  const float* Wo = (const float*)d_in[5];
  const float* bo = (const float*)d_in[6];
  float* out = (float*)d_out;

  const int M = NB * S_LEN;  // 4096
  u16*   Qws  = (u16*)d_ws;                    // 8 MB
  u16*   Cws  = Qws + (size_t)M * DIM;         // 8 MB
  u16*   xbf  = Cws + (size_t)M * DIM;         // 8 MB
  u16*   Wqbf = xbf + (size_t)M * DIM;         // 2 MB
  u16*   Wobf = Wqbf + (size_t)DIM * DIM;      // 2 MB
  float* CTXf = (float*)(Wobf + (size_t)DIM * DIM);  // 16 MB
  float* Mb   = CTXf + (size_t)M * DIM;        // 256 KB
  float* Lb   = Mb + (size_t)NB * NH * S_LEN;  // 256 KB

  const int n4x = M * DIM / 4, n4w = DIM * DIM / 4;
  cvt_f32_bf16<<<(n4x + 255) / 256, 256, 0, stream>>>(x, xbf, n4x);
  cvt_f32_bf16<<<(n4w + 255) / 256, 256, 0, stream>>>(Wq, Wqbf, n4w);
  cvt_f32_bf16<<<(n4w + 255) / 256, 256, 0, stream>>>(Wo, Wobf, n4w);

  gemm_bt<false, u16><<<dim3(DIM / 128, M / 128), 256, 0, stream>>>(
      xbf, Wqbf, bq, Qws, M, DIM, DIM);
  attn<<<dim3(S_LEN / 64, NH, NB), 256, 0, stream>>>(Qws, xbf, CTXf, Mb, Lb);
  finalize<<<NB * NH * S_LEN / 4, 256, 0, stream>>>(Qws, pq, pv, CTXf, Mb, Lb, Cws);
  gemm_bt<true, float><<<dim3(DIM / 128, M / 128), 256, 0, stream>>>(
      Cws, Wobf, bo, out, M, DIM, DIM);
}

// Round 3
// 169.635 us; speedup vs baseline: 1.3929x; 1.3871x over previous
//
#include <hip/hip_runtime.h>
#include <hip/hip_bf16.h>
#include <math.h>

#define S_LEN 2048
#define DIM   1024
#define NH    16
#define NL    4
#define NB    2
#define PARTS_PER_BH 80   // sum over 32 q-tiles of ceil((qt+1)/8)

typedef __attribute__((ext_vector_type(8))) short bf16x8;
typedef __attribute__((ext_vector_type(4))) float f32x4;
typedef unsigned short u16;

__device__ __forceinline__ float bf2f(u16 u) {
  union { unsigned int i; float f; } x; x.i = ((unsigned int)u) << 16; return x.f;
}
__device__ __forceinline__ u16 f2bf(float f) {  // RNE
  union { float f; unsigned int i; } x; x.f = f;
  unsigned int r = x.i + 0x7fffu + ((x.i >> 16) & 1u);
  return (u16)(r >> 16);
}

__device__ __forceinline__ void g2l16(const void* g, void* l) {
  __builtin_amdgcn_global_load_lds(
      (const __attribute__((address_space(1))) void*)g,
      (__attribute__((address_space(3))) void*)l, 16, 0, 0);
}

// DPP lane permute (VALU-speed, no LDS). CTRL: 0xB1=xor1, 0x4E=xor2,
// 0x141=row_half_mirror (acts as xor4 on 4-aligned partials),
// 0x140=row_mirror (acts as xor8 on 8-aligned partials).
template <int CTRL>
__device__ __forceinline__ float dppf(float x) {
  union { float f; int i; } u, r;
  u.f = x;
  r.i = __builtin_amdgcn_update_dpp(0, u.i, CTRL, 0xF, 0xF, true);
  return r.f;
}
__device__ __forceinline__ float rmax16(float x) {
  x = fmaxf(x, dppf<0xB1>(x));
  x = fmaxf(x, dppf<0x4E>(x));
  x = fmaxf(x, dppf<0x141>(x));
  x = fmaxf(x, dppf<0x140>(x));
  return x;
}
__device__ __forceinline__ float rsum16(float x) {
  x += dppf<0xB1>(x);
  x += dppf<0x4E>(x);
  x += dppf<0x141>(x);
  x += dppf<0x140>(x);
  return x;
}

__global__ void cvt_f32_bf16(const float* __restrict__ in, u16* __restrict__ out, int n4) {
  int i = blockIdx.x * blockDim.x + threadIdx.x;
  if (i >= n4) return;
  float4 v = ((const float4*)in)[i];
  ushort4 o;
  o.x = f2bf(v.x); o.y = f2bf(v.y); o.z = f2bf(v.z); o.w = f2bf(v.w);
  ((ushort4*)out)[i] = o;
}

// C = act(A @ Bt^T + bias). 128x128 tile, BK=64, 4 waves (2x2).
template <bool GELU, typename OT>
__global__ __launch_bounds__(256)
void gemm_bt(const u16* __restrict__ A, const u16* __restrict__ Bt,
             const float* __restrict__ bias, OT* __restrict__ C,
             int M, int N, int K) {
  __shared__ u16 As[128 * 64];
  __shared__ u16 Bs[128 * 64];
  const int lane = threadIdx.x & 63, wave = threadIdx.x >> 6;
  const int ln = lane & 15, g = lane >> 4;
  const int m0 = blockIdx.y * 128, n0 = blockIdx.x * 128;
  const int wm = wave >> 1, wn = wave & 1;
  f32x4 acc[4][4] = {};

  for (int k0 = 0; k0 < K; k0 += 64) {
    __syncthreads();
#pragma unroll
    for (int rd = 0; rd < 4; ++rd) {
      int chunk = rd * 4 + wave;
      int flat = chunk * 1024 + lane * 16;
      int row = flat >> 7;
      int within = (flat & 127) ^ ((row & 7) << 4);
      g2l16((const char*)A + ((size_t)(m0 + row) * K + k0) * 2 + within,
            (char*)As + chunk * 1024);
      g2l16((const char*)Bt + ((size_t)(n0 + row) * K + k0) * 2 + within,
            (char*)Bs + chunk * 1024);
    }
    __syncthreads();
#pragma unroll
    for (int kc = 0; kc < 2; ++kc) {
      bf16x8 af[4], bfr[4];
#pragma unroll
      for (int i = 0; i < 4; ++i) {
        int ra = wm * 64 + i * 16 + ln;
        af[i] = *(const bf16x8*)((const char*)As + ra * 128 +
                                 ((kc * 64 + g * 16) ^ ((ra & 7) << 4)));
        int rb = wn * 64 + i * 16 + ln;
        bfr[i] = *(const bf16x8*)((const char*)Bs + rb * 128 +
                                  ((kc * 64 + g * 16) ^ ((rb & 7) << 4)));
      }
#pragma unroll
      for (int i = 0; i < 4; ++i)
#pragma unroll
        for (int j = 0; j < 4; ++j)
          acc[i][j] = __builtin_amdgcn_mfma_f32_16x16x32_bf16(af[i], bfr[j], acc[i][j], 0, 0, 0);
    }
  }

#pragma unroll
  for (int j = 0; j < 4; ++j) {
    int gc = n0 + wn * 64 + j * 16 + ln;
    float bv = bias[gc];
#pragma unroll
    for (int i = 0; i < 4; ++i) {
      int gr0 = m0 + wm * 64 + i * 16 + g * 4;
#pragma unroll
      for (int r = 0; r < 4; ++r) {
        float v = acc[i][j][r] + bv;
        if constexpr (GELU) v = 0.5f * v * (1.0f + erff(v * 0.70710678118f));
        if constexpr (sizeof(OT) == 2) C[(size_t)(gr0 + r) * N + gc] = (OT)f2bf(v);
        else                           C[(size_t)(gr0 + r) * N + gc] = (OT)v;
      }
    }
  }
}

// Flash self-attention, token part, K-chunked (flash-decoding style).
// grid (PARTS_PER_BH, H, B); each block handles one q-tile x <=8 key-tiles,
// writes unnormalized partial ctx + (m,l). Double-buffered K/V staging with
// prefetch; DPP-based row reduces.
__global__ __launch_bounds__(256)
void attn(const u16* __restrict__ Q, const u16* __restrict__ Xb,
          float* __restrict__ CTXP, float* __restrict__ MP, float* __restrict__ LP) {
  __shared__ u16 Ks[2][64 * 64];
  __shared__ u16 Vt[2][64 * 64];
  __shared__ u16 Pw[4][16 * 64];

  const int lane = threadIdx.x & 63, wave = threadIdx.x >> 6;
  const int ln = lane & 15, g = lane >> 4;
  const int h = blockIdx.y, b = blockIdx.z;

  // decode part -> (qt, chunk)
  const int p = blockIdx.x;
  int qt, chunk;
  if (p < 8)       { qt = p;                          chunk = 0; }
  else if (p < 24) { int i = p - 8;  qt = 8 + (i >> 1);  chunk = i & 1; }
  else if (p < 48) { int i = p - 24; qt = 16 + i / 3;    chunk = i % 3; }
  else             { int i = p - 48; qt = 24 + (i >> 2); chunk = i & 3; }
  const int kt0 = chunk * 8;
  const int kt1e = kt0 + 8 < qt + 1 ? kt0 + 8 : qt + 1;

  const size_t qrow = (size_t)b * S_LEN + qt * 64 + wave * 16 + ln;
  const bf16x8 qa0 = *(const bf16x8*)(Q + qrow * DIM + h * 64 + g * 8);
  const bf16x8 qa1 = *(const bf16x8*)(Q + qrow * DIM + h * 64 + 32 + g * 8);

  f32x4 acc[4] = {};
  float m_run[4] = {-INFINITY, -INFINITY, -INFINITY, -INFINITY};
  float l_run[4] = {0.f, 0.f, 0.f, 0.f};

  const int tid = threadIdx.x;
  const int vr0 = (tid >> 3) * 2;   // key row pair
  const int vc0 = (tid & 7) * 8;    // dim cols

  // prologue: stage tile kt0 into buffer 0
  {
    const u16* xsrc = Xb + ((size_t)b * S_LEN + kt0 * 64 + vr0) * DIM + h * 64 + vc0;
    bf16x8 r0 = *(const bf16x8*)xsrc;
    bf16x8 r1 = *(const bf16x8*)(xsrc + DIM);
#pragma unroll
    for (int rd = 0; rd < 2; ++rd) {
      int ch = rd * 4 + wave;
      int flat = ch * 1024 + lane * 16;
      int row = flat >> 7;
      int within = (flat & 127) ^ ((row & 7) << 4);
      g2l16((const char*)Q + (((size_t)b * S_LEN + kt0 * 64 + row) * DIM + h * 64) * 2 + within,
            (char*)Ks[0] + ch * 1024);
    }
#pragma unroll
    for (int j = 0; j < 8; ++j) {
      int c = vc0 + j;
      unsigned int pack = (unsigned int)(u16)r0[j] | ((unsigned int)(u16)r1[j] << 16);
      *(unsigned int*)((char*)Vt[0] + c * 128 + ((vr0 * 2) ^ ((c & 7) << 4))) = pack;
    }
  }
  __syncthreads();

  for (int kt = kt0; kt < kt1e; ++kt) {
    const int cur = (kt - kt0) & 1, nxt = cur ^ 1;
    const bool more = (kt + 1 < kt1e);
    bf16x8 nr0, nr1;
    if (more) {
      // prefetch next tile: V to regs, K via global_load_lds
      const u16* xsrc = Xb + ((size_t)b * S_LEN + (kt + 1) * 64 + vr0) * DIM + h * 64 + vc0;
      nr0 = *(const bf16x8*)xsrc;
      nr1 = *(const bf16x8*)(xsrc + DIM);
#pragma unroll
      for (int rd = 0; rd < 2; ++rd) {
        int ch = rd * 4 + wave;
        int flat = ch * 1024 + lane * 16;
        int row = flat >> 7;
        int within = (flat & 127) ^ ((row & 7) << 4);
        g2l16((const char*)Q + (((size_t)b * S_LEN + (kt + 1) * 64 + row) * DIM + h * 64) * 2 + within,
              (char*)Ks[nxt] + ch * 1024);
      }
      __builtin_amdgcn_sched_barrier(0);  // pin prefetch issue above compute
    }

    // QK^T from Ks[cur]
    float pv_[4][4];
#pragma unroll
    for (int sub = 0; sub < 4; ++sub) {
      int kr = sub * 16 + ln;
      bf16x8 kb0 = *(const bf16x8*)((const char*)Ks[cur] + kr * 128 + ((g * 16) ^ ((kr & 7) << 4)));
      bf16x8 kb1 = *(const bf16x8*)((const char*)Ks[cur] + kr * 128 + ((64 + g * 16) ^ ((kr & 7) << 4)));
      f32x4 c = {};
      c = __builtin_amdgcn_mfma_f32_16x16x32_bf16(qa0, kb0, c, 0, 0, 0);
      c = __builtin_amdgcn_mfma_f32_16x16x32_bf16(qa1, kb1, c, 0, 0, 0);
#pragma unroll
      for (int r = 0; r < 4; ++r) {
        float s = c[r] * 0.125f;
        if (kt == qt) {
          int key = sub * 16 + ln;
          int qi = wave * 16 + g * 4 + r;
          if (key > qi) s = -INFINITY;
        }
        pv_[sub][r] = s;
      }
    }
    // online softmax; rows live in 16-lane groups -> DPP reduces
    float scl[4];
#pragma unroll
    for (int r = 0; r < 4; ++r) {
      float t = rmax16(fmaxf(fmaxf(pv_[0][r], pv_[1][r]), fmaxf(pv_[2][r], pv_[3][r])));
      float mn = fmaxf(m_run[r], t);
      scl[r] = __expf(m_run[r] - mn);
      m_run[r] = mn;
    }
#pragma unroll
    for (int sub = 0; sub < 4; ++sub)
#pragma unroll
      for (int r = 0; r < 4; ++r) pv_[sub][r] = __expf(pv_[sub][r] - m_run[r]);
#pragma unroll
    for (int r = 0; r < 4; ++r) {
      float su = rsum16(pv_[0][r] + pv_[1][r] + pv_[2][r] + pv_[3][r]);
      l_run[r] = l_run[r] * scl[r] + su;
    }
#pragma unroll
    for (int ns = 0; ns < 4; ++ns)
#pragma unroll
      for (int r = 0; r < 4; ++r) acc[ns][r] *= scl[r];

    // P: C-layout -> LDS -> A-layout (per-wave private)
#pragma unroll
    for (int sub = 0; sub < 4; ++sub)
#pragma unroll
      for (int r = 0; r < 4; ++r) {
        int pr = g * 4 + r;
        *(u16*)((char*)Pw[wave] + pr * 128 + (((sub * 16 + ln) * 2) ^ ((pr & 7) << 4))) =
            f2bf(pv_[sub][r]);
      }
    bf16x8 pa0 = *(const bf16x8*)((const char*)Pw[wave] + ln * 128 + ((g * 16) ^ ((ln & 7) << 4)));
    bf16x8 pa1 = *(const bf16x8*)((const char*)Pw[wave] + ln * 128 + ((64 + g * 16) ^ ((ln & 7) << 4)));
#pragma unroll
    for (int ns = 0; ns < 4; ++ns) {
      int vr = ns * 16 + ln;
      bf16x8 vb0 = *(const bf16x8*)((const char*)Vt[cur] + vr * 128 + ((g * 16) ^ ((vr & 7) << 4)));
      bf16x8 vb1 = *(const bf16x8*)((const char*)Vt[cur] + vr * 128 + ((64 + g * 16) ^ ((vr & 7) << 4)));
      acc[ns] = __builtin_amdgcn_mfma_f32_16x16x32_bf16(pa0, vb0, acc[ns], 0, 0, 0);
      acc[ns] = __builtin_amdgcn_mfma_f32_16x16x32_bf16(pa1, vb1, acc[ns], 0, 0, 0);
    }

    if (more) {
      // write prefetched V^T into next buffer (waits V regs; K drains at barrier)
#pragma unroll
      for (int j = 0; j < 8; ++j) {
        int c = vc0 + j;
        unsigned int pack = (unsigned int)(u16)nr0[j] | ((unsigned int)(u16)nr1[j] << 16);
        *(unsigned int*)((char*)Vt[nxt] + c * 128 + ((vr0 * 2) ^ ((c & 7) << 4))) = pack;
      }
    }
    __syncthreads();
  }

  // write unnormalized partial ctx + stats
  const size_t slot = ((size_t)(b * NH + h)) * PARTS_PER_BH + p;
#pragma unroll
  for (int ns = 0; ns < 4; ++ns)
#pragma unroll
    for (int r = 0; r < 4; ++r) {
      int qr = wave * 16 + g * 4 + r;
      CTXP[slot * 4096 + (size_t)qr * 64 + ns * 16 + ln] = acc[ns][r];
    }
  if (ln == 0) {
#pragma unroll
    for (int r = 0; r < 4; ++r) {
      int qr = wave * 16 + g * 4 + r;
      MP[slot * 64 + qr] = m_run[r];
      LP[slot * 64 + qr] = l_run[r];
    }
  }
}

// Merge K-chunk partials + fold L=4 memory slots, produce final bf16 ctx.
// One wave per (b,h,s) row.
__global__ __launch_bounds__(256)
void finalize(const u16* __restrict__ Q, const float* __restrict__ PQ,
              const float* __restrict__ PV, const float* __restrict__ CTXP,
              const float* __restrict__ MP, const float* __restrict__ LP,
              u16* __restrict__ Cout) {
  const int lane = threadIdx.x & 63, wave = threadIdx.x >> 6;
  const size_t row = (size_t)blockIdx.x * 4 + wave;  // (b*H+h)*S + s
  const int s = (int)(row & (S_LEN - 1));
  const int h = (int)((row >> 11) & (NH - 1));
  const int b = (int)(row >> 15);

  const int qt = s >> 6, G = qt >> 3, parts = G + 1;
  const int baseG[4] = {0, 8, 24, 48};
  const int p0 = baseG[G] + (qt & 7) * parts;
  const size_t slot0 = ((size_t)(b * NH + h)) * PARTS_PER_BH + p0;
  const int sr = s & 63;

  // merge partials (unnormalized)
  float mc[4], lc[4];
  float m_tok = -INFINITY;
#pragma unroll
  for (int c = 0; c < 4; ++c)
    if (c < parts) {
      mc[c] = MP[(slot0 + c) * 64 + sr];
      lc[c] = LP[(slot0 + c) * 64 + sr];
      m_tok = fmaxf(m_tok, mc[c]);
    }
  float l_tok = 0.f, cd = 0.f;
#pragma unroll
  for (int c = 0; c < 4; ++c)
    if (c < parts) {
      float w = __expf(mc[c] - m_tok);
      l_tok += w * lc[c];
      cd += w * CTXP[(slot0 + c) * 4096 + (size_t)sr * 64 + lane];
    }

  // memory slots
  const float qd = bf2f(Q[((size_t)b * S_LEN + s) * DIM + h * 64 + lane]);
  const float* pq = PQ + row * (NL * 64);
  const float* pv = PV + row * (NL * 64);
  float msc[NL];
  float m_fin = m_tok;
#pragma unroll
  for (int lm = 0; lm < NL; ++lm) {
    float prod = qd * pq[lm * 64 + lane];
#pragma unroll
    for (int o = 1; o < 64; o <<= 1) prod += __shfl_xor(prod, o);
    msc[lm] = prod * 0.125f;
    m_fin = fmaxf(m_fin, msc[lm]);
  }
  const float a = __expf(m_tok - m_fin);
  float l_fin = l_tok * a;
  cd *= a;
#pragma unroll
  for (int lm = 0; lm < NL; ++lm) {
    float w = __expf(msc[lm] - m_fin);
    l_fin += w;
    cd += w * pv[lm * 64 + lane];
  }
  Cout[((size_t)b * S_LEN + s) * DIM + h * 64 + lane] = f2bf(cd / l_fin);
}

extern "C" void kernel_launch(void* const* d_in, const int* in_sizes, int n_in,
                              void* d_out, int out_size, void* d_ws, size_t ws_size,
                              hipStream_t stream) {
  const float* x  = (const float*)d_in[0];
  const float* pq = (const float*)d_in[1];
  const float* pv = (const float*)d_in[2];
  const float* Wq = (const float*)d_in[3];
  const float* bq = (const float*)d_in[4];
  const float* Wo = (const float*)d_in[5];
  const float* bo = (const float*)d_in[6];
  float* out = (float*)d_out;

  const int M = NB * S_LEN;  // 4096
  u16*   Qws  = (u16*)d_ws;                    // 8 MB
  u16*   Cws  = Qws + (size_t)M * DIM;         // 8 MB
  u16*   xbf  = Cws + (size_t)M * DIM;         // 8 MB
  u16*   Wqbf = xbf + (size_t)M * DIM;         // 2 MB
  u16*   Wobf = Wqbf + (size_t)DIM * DIM;      // 2 MB
  float* CTXP = (float*)(Wobf + (size_t)DIM * DIM);          // 2560*4096 f32 = 42 MB
  float* MP   = CTXP + (size_t)NB * NH * PARTS_PER_BH * 4096; // 640 KB
  float* LP   = MP + (size_t)NB * NH * PARTS_PER_BH * 64;     // 640 KB

  const int n4x = M * DIM / 4, n4w = DIM * DIM / 4;
  cvt_f32_bf16<<<(n4x + 255) / 256, 256, 0, stream>>>(x, xbf, n4x);
  cvt_f32_bf16<<<(n4w + 255) / 256, 256, 0, stream>>>(Wq, Wqbf, n4w);
  cvt_f32_bf16<<<(n4w + 255) / 256, 256, 0, stream>>>(Wo, Wobf, n4w);

  gemm_bt<false, u16><<<dim3(DIM / 128, M / 128), 256, 0, stream>>>(
      xbf, Wqbf, bq, Qws, M, DIM, DIM);
  attn<<<dim3(PARTS_PER_BH, NH, NB), 256, 0, stream>>>(Qws, xbf, CTXP, MP, LP);
  finalize<<<NB * NH * S_LEN / 4, 256, 0, stream>>>(Qws, pq, pv, CTXP, MP, LP, Cws);
  gemm_bt<true, float><<<dim3(DIM / 128, M / 128), 256, 0, stream>>>(
      Cws, Wobf, bo, out, M, DIM, DIM);
}